// Round 8
// baseline (119.635 us; speedup 1.0000x reference)
//
#include <hip/hip_runtime.h>

#define INV_T (1.0f / 0.07f)
#define EPSF 1e-8f

typedef __bf16 bf16x8 __attribute__((ext_vector_type(8)));
typedef float f32x4 __attribute__((ext_vector_type(4)));

struct TrueT { static constexpr bool value = true; };
struct FalseT { static constexpr bool value = false; };

__device__ __forceinline__ unsigned short f2b(float x) {
  union { float f; unsigned u; } a; a.f = x;
  return (unsigned short)((a.u + 0x7fffu + ((a.u >> 16) & 1u)) >> 16);
}

__device__ __forceinline__ void gld16(const void* g, void* l) {
  __builtin_amdgcn_global_load_lds(
      (const __attribute__((address_space(1))) unsigned int*)g,
      (__attribute__((address_space(3))) unsigned int*)l, 16, 0, 0);
}

// 4 rows per block (one per wave): L2-normalize, cast to bf16.
// Block 0 also zeroes the 2-float loss accumulator.
__global__ __launch_bounds__(256) void norm_kernel(const float* __restrict__ emb,
                                                   unsigned short* __restrict__ ebf,
                                                   float* __restrict__ acc2,
                                                   int D) {
  const int wave = threadIdx.x >> 6;
  const int lane = threadIdx.x & 63;
  const int row = blockIdx.x * 4 + wave;
  const float4* src = (const float4*)(emb + (size_t)row * D);
  float4 v0 = src[lane];
  float4 v1 = src[lane + 64];
  float ss = v0.x * v0.x + v0.y * v0.y + v0.z * v0.z + v0.w * v0.w +
             v1.x * v1.x + v1.y * v1.y + v1.z * v1.z + v1.w * v1.w;
#pragma unroll
  for (int m = 32; m >= 1; m >>= 1) ss += __shfl_xor(ss, m, 64);
  const float r = 1.0f / sqrtf(ss);
  ushort4 o0, o1;
  o0.x = f2b(v0.x * r); o0.y = f2b(v0.y * r); o0.z = f2b(v0.z * r); o0.w = f2b(v0.w * r);
  o1.x = f2b(v1.x * r); o1.y = f2b(v1.y * r); o1.z = f2b(v1.z * r); o1.w = f2b(v1.w * r);
  ushort4* dst = (ushort4*)(ebf + (size_t)row * D);
  dst[lane] = o0;
  dst[lane + 64] = o1;
  if (blockIdx.x == 0 && threadIdx.x < 2) acc2[threadIdx.x] = 0.f;
}

// Upper-block-triangle of sim = e.e^T. 256x256 tile, BK=32, 8 waves (2Mx4N).
// 2-phase double buffer (verified r5-r7). NO global atomics: per-block row/col
// partials are combined in LDS and stored to private planes:
//   rowpart[plane=bb][N] <- rows i0..i0+255 of block (ba,bb)
//   colpart[plane=ba][N] <- cols j0..j0+255 of block (ba,bb)  (off-diag only)
// Every slot the reducer reads is written unconditionally -> no zeroing.
__global__ __launch_bounds__(512, 2) void sim_kernel(
    const unsigned short* __restrict__ E,   // bf16 normalized, N x D
    const int* __restrict__ labels,         // int32 (harness converts int64)
    float* __restrict__ rp_d, float* __restrict__ rp_n,
    float* __restrict__ cp_d, float* __restrict__ cp_n,
    int D, int kTiles, int N) {
  __shared__ unsigned short lds[2][2][256 * 32];  // [buf][A/B], 16KB each, 64KB
  __shared__ float srd[4][256], srn[4][256];      // row partials per wn
  __shared__ float scd[2][256], scn[2][256];      // col partials per wm

  const int tid = threadIdx.x;
  const int lane = tid & 63;
  const int wave = tid >> 6;               // 0..7
  const int wm = wave >> 2, wn = wave & 3; // 2x4 wave grid: 128x64 per wave
  const int fr = lane & 15;
  const int fk = lane >> 4;

  // XCD-aware swizzle (528 % 8 == 0), then triangular decode
  const int bid = blockIdx.x;
  const int t = (bid & 7) * 66 + (bid >> 3);
  int bb = (int)((sqrtf(8.0f * (float)t + 1.0f) - 1.0f) * 0.5f);
  while ((bb + 1) * (bb + 2) / 2 <= t) ++bb;
  while (bb * (bb + 1) / 2 > t) --bb;
  const int ba = t - bb * (bb + 1) / 2;
  const int i0 = ba * 256;
  const int j0 = bb * 256;
  const bool diag = (i0 == j0);

  f32x4 acc[8][4] = {};

  const int swz = ((fr >> 1) & 3) << 4;
  const int cbk = (fk * 16) ^ swz;
  int aoff[8], boff[4];
#pragma unroll
  for (int m = 0; m < 8; ++m) aoff[m] = (wm * 128 + m * 16 + fr) * 64 + cbk;
#pragma unroll
  for (int n = 0; n < 4; ++n) boff[n] = (wn * 64 + n * 16 + fr) * 64 + cbk;

  auto stage = [&](int buf, int kt) {
    const int kbase = kt * 32;
#pragma unroll
    for (int c = 0; c < 2; ++c) {
      const int lo = c * 8192 + tid * 16;            // byte offset in 16KB tile
      const int row = lo >> 6;                       // 64B per row
      const int scb = (lo & 63) ^ (((row >> 1) & 3) << 4);
      const unsigned short* gA = E + (size_t)(i0 + row) * D + kbase + (scb >> 1);
      const unsigned short* gB = E + (size_t)(j0 + row) * D + kbase + (scb >> 1);
      gld16(gA, &lds[buf][0][lo >> 1]);
      gld16(gB, &lds[buf][1][lo >> 1]);
    }
  };

  auto compute = [&](int cb) {
    const char* Ab = (const char*)&lds[cb][0][0];
    const char* Bb = (const char*)&lds[cb][1][0];
    bf16x8 a[8], b[4];
#pragma unroll
    for (int m = 0; m < 8; ++m) a[m] = *(const bf16x8*)(Ab + aoff[m]);
#pragma unroll
    for (int n = 0; n < 4; ++n) b[n] = *(const bf16x8*)(Bb + boff[n]);
    __builtin_amdgcn_s_setprio(1);
#pragma unroll
    for (int m = 0; m < 8; ++m)
#pragma unroll
      for (int n = 0; n < 4; ++n)
        acc[m][n] = __builtin_amdgcn_mfma_f32_16x16x32_bf16(a[m], b[n], acc[m][n], 0, 0, 0);
    __builtin_amdgcn_s_setprio(0);
  };

  stage(0, 0);
  asm volatile("s_waitcnt vmcnt(0)" ::: "memory");
  __builtin_amdgcn_s_barrier();

  int cur = 0;
  for (int kt = 0; kt < kTiles; ++kt) {
    if (kt + 1 < kTiles) stage(cur ^ 1, kt + 1);
    compute(cur);
    asm volatile("s_waitcnt vmcnt(0) lgkmcnt(0)" ::: "memory");
    __builtin_amdgcn_s_barrier();
    cur ^= 1;
  }

  // ---- epilogue: per-wave partials (verified), scatter via LDS + stores ----
  // acc[m][n][r]: i = i0 + wm*128 + m*16 + fk*4 + r ; j = j0 + wn*64 + n*16 + fr
  int jcol[4], labj[4];
#pragma unroll
  for (int n = 0; n < 4; ++n) {
    jcol[n] = j0 + wn * 64 + n * 16 + fr;
    labj[n] = labels[jcol[n]];
  }
  float cd[4] = {0.f, 0.f, 0.f, 0.f}, cn[4] = {0.f, 0.f, 0.f, 0.f};

  auto epilogue = [&](auto DIAG) {
#pragma unroll
    for (int m = 0; m < 8; ++m) {
      float pdm[4] = {0.f, 0.f, 0.f, 0.f}, pnm[4] = {0.f, 0.f, 0.f, 0.f};
      const int ibase = i0 + wm * 128 + m * 16 + fk * 4;
      int li[4];
#pragma unroll
      for (int r = 0; r < 4; ++r) li[r] = labels[ibase + r];
#pragma unroll
      for (int n = 0; n < 4; ++n) {
#pragma unroll
        for (int r = 0; r < 4; ++r) {
          const float s = acc[m][n][r] * INV_T;
          const float es = __expf(s);
          if (DIAG.value) {
            if (jcol[n] != ibase + r) {
              pdm[r] += es;
              if (li[r] == labj[n] && s > 0.0f) pnm[r] += es;
            }
          } else {
            pdm[r] += es;
            cd[n] += es;
            if (li[r] == labj[n] && s > 0.0f) { pnm[r] += es; cn[n] += es; }
          }
        }
      }
#pragma unroll
      for (int sh = 1; sh < 16; sh <<= 1) {
#pragma unroll
        for (int r = 0; r < 4; ++r) {
          pdm[r] += __shfl_xor(pdm[r], sh, 64);
          pnm[r] += __shfl_xor(pnm[r], sh, 64);
        }
      }
      if (fr == 0) {
        const int rbase = wm * 128 + m * 16 + fk * 4;
#pragma unroll
        for (int r = 0; r < 4; ++r) {
          srd[wn][rbase + r] = pdm[r];
          srn[wn][rbase + r] = pnm[r];
        }
      }
    }
  };

  if (diag) epilogue(TrueT{}); else epilogue(FalseT{});

  if (!diag) {
    // col partials: j depends on (n, fr) only; reduce over fk (lanes xor 16,32)
#pragma unroll
    for (int sh = 16; sh < 64; sh <<= 1) {
#pragma unroll
      for (int n = 0; n < 4; ++n) {
        cd[n] += __shfl_xor(cd[n], sh, 64);
        cn[n] += __shfl_xor(cn[n], sh, 64);
      }
    }
    if (fk == 0) {
#pragma unroll
      for (int n = 0; n < 4; ++n) {
        scd[wm][wn * 64 + n * 16 + fr] = cd[n];
        scn[wm][wn * 64 + n * 16 + fr] = cn[n];
      }
    }
  }

  __syncthreads();
  const int t2 = tid & 255;
  if (tid < 256) {
    rp_d[(size_t)bb * N + i0 + t2] = srd[0][t2] + srd[1][t2] + srd[2][t2] + srd[3][t2];
    if (!diag) cp_d[(size_t)ba * N + j0 + t2] = scd[0][t2] + scd[1][t2];
  } else {
    rp_n[(size_t)bb * N + i0 + t2] = srn[0][t2] + srn[1][t2] + srn[2][t2] + srn[3][t2];
    if (!diag) cp_n[(size_t)ba * N + j0 + t2] = scn[0][t2] + scn[1][t2];
  }
}

// Per-row: den = sum of 32 planes (rowpart for p>=ba_i, colpart below);
// loss_i; block reduce; 2 atomicAdds into acc2.
__global__ __launch_bounds__(256) void reduce_kernel(
    const float* __restrict__ rp_d, const float* __restrict__ rp_n,
    const float* __restrict__ cp_d, const float* __restrict__ cp_n,
    float* __restrict__ acc2, int N, int NB) {
  const int tid = threadIdx.x;
  const int i = blockIdx.x * 256 + tid;
  const int bai = i >> 8;
  float d = 0.f, n = 0.f;
  for (int p = 0; p < NB; ++p) {
    d += (p >= bai) ? rp_d[(size_t)p * N + i] : cp_d[(size_t)p * N + i];
    n += (p >= bai) ? rp_n[(size_t)p * N + i] : cp_n[(size_t)p * N + i];
  }
  float sum = 0.f, cnt = 0.f;
  if (n > 0.f && d > 0.f) {
    sum = logf(d + EPSF) - logf(n);
    cnt = 1.f;
  }
#pragma unroll
  for (int m = 32; m >= 1; m >>= 1) {
    sum += __shfl_xor(sum, m, 64);
    cnt += __shfl_xor(cnt, m, 64);
  }
  __shared__ float s1[4], s2[4];
  if ((tid & 63) == 0) { s1[tid >> 6] = sum; s2[tid >> 6] = cnt; }
  __syncthreads();
  if (tid == 0) {
    atomicAdd(&acc2[0], s1[0] + s1[1] + s1[2] + s1[3]);
    atomicAdd(&acc2[1], s2[0] + s2[1] + s2[2] + s2[3]);
  }
}

__global__ void final_kernel(const float* __restrict__ acc2, float* __restrict__ out) {
  const float S = acc2[0], C = acc2[1];
  out[0] = (C > 0.f) ? fabsf(S / C) : 0.f;
}

extern "C" void kernel_launch(void* const* d_in, const int* in_sizes, int n_in,
                              void* d_out, int out_size, void* d_ws, size_t ws_size,
                              hipStream_t stream) {
  const float* emb = (const float*)d_in[0];
  const int* labels = (const int*)d_in[1];
  float* out = (float*)d_out;

  const int N = in_sizes[1];          // 8192
  const int D = in_sizes[0] / N;      // 512
  const int NB = N / 256;             // 32

  char* ws = (char*)d_ws;
  unsigned short* ebf = (unsigned short*)ws;            // N*D*2 = 8 MB
  size_t off = (size_t)N * D * 2;
  float* rp_d = (float*)(ws + off); off += (size_t)NB * N * 4;   // 1 MB
  float* rp_n = (float*)(ws + off); off += (size_t)NB * N * 4;
  float* cp_d = (float*)(ws + off); off += (size_t)NB * N * 4;
  float* cp_n = (float*)(ws + off); off += (size_t)NB * N * 4;
  float* acc2 = (float*)(ws + off);

  norm_kernel<<<N / 4, 256, 0, stream>>>(emb, ebf, acc2, D);
  const int tri = NB * (NB + 1) / 2;            // 528
  sim_kernel<<<tri, 512, 0, stream>>>(ebf, labels, rp_d, rp_n, cp_d, cp_n,
                                      D, D / 32, N);
  reduce_kernel<<<N / 256, 256, 0, stream>>>(rp_d, rp_n, cp_d, cp_n, acc2, N, NB);
  final_kernel<<<1, 1, 0, stream>>>(acc2, out);
}